// Round 14
// baseline (113.617 us; speedup 1.0000x reference)
//
#include <hip/hip_runtime.h>

#define D_ 8
#define B_ 32
#define PRE_ 1024
#define POST_ 1024

// exp(-1/10), exp(-1/20), exp(-1/15)
#define ALPHA_P 0.90483741803595952f
#define ALPHA_D 0.95122942450071400f
#define ALPHA_X 0.93550698503161731f

#define NMAIN PRE_                                            // 1024 main blocks
#define NFILT (((D_*B_*PRE_)/4 + 2*((B_*POST_)/4)) / 256)     // 320 filter blocks

typedef float f32x4 __attribute__((ext_vector_type(4)));
typedef float f32x2 __attribute__((ext_vector_type(2)));
typedef unsigned short u16x4 __attribute__((ext_vector_type(4)));

// R13 (best: 82.4 us) with ONE change: PLAIN stores instead of NT stores.
//   R13 proved the NT LOAD path was the big throttle (105 -> 82.4 by switching
//   to cached load; NT bypasses L2, shallow request queue, invisible to FETCH).
//   The stores still use that path family. R11's "plain stores worse" verdict
//   (109 vs 105) was measured UNDER the NT-load bottleneck -> confounded.
//   Fill kernel reference (7 TB/s) uses plain stores.
//   If this regresses: L2 write-allocate pollution is real -> revert to R13 and
//   declare roofline (~5.7 of 6.5-7 TB/s achievable).
//   Everything else identical to R13:
//   - Plain cached W load (the R13 win).
//   - bf16 dmap e-slice in LDS (16 KB, zero cross-thread sharing -> lossy ok,
//     absmax 0.0078 vs threshold 0.083).
//   - __launch_bounds__(256,2) only. R9: (256,6)->40 VGPR serializes loads;
//     R4: (256,8)->32 VGPR scratch-spills. Never cap below natural live state.
__global__ __launch_bounds__(256, 2) void clopath_fused(
    const float* __restrict__ W,
    const float* __restrict__ dmap,
    const float* __restrict__ A_p,
    const float* __restrict__ A_d,
    const float* __restrict__ wmax,
    const float* __restrict__ xbar_pre,
    const float* __restrict__ Xd,
    const float* __restrict__ Xpost,
    const float* __restrict__ Vpost,
    const float* __restrict__ u_pot,
    const float* __restrict__ u_dep,
    float* __restrict__ out,       // output 0: copy of W
    float* __restrict__ W_new,     // output 1
    float* __restrict__ xbar_new,  // output 2
    float* __restrict__ u_pot_new, // output 3
    float* __restrict__ u_dep_new) // output 4
{
    const int bid = blockIdx.x;
    const int tid = threadIdx.x;

    if (bid < NMAIN) {
        const int e = bid;                 // one block per e
        const int o = tid << 2;            // this thread's float4 of POST

        __shared__ unsigned short dm16[D_ * POST_];  // 16 KB: bf16 dmap e-slice
        __shared__ float xbd_lds[B_ * D_ * 2];       // 2 KB: (xb, xd) per (b,d)

        // Stage (xb, xd) pairs: t -> (b = t>>3, d = t&7)
        {
            const int d = tid & 7;
            const int b = tid >> 3;
            const size_t idx = ((size_t)(d * B_ + b)) * PRE_ + e;
            f32x2 p;
            p.x = xbar_pre[idx];
            p.y = Xd[idx];
            *reinterpret_cast<f32x2*>(&xbd_lds[(b * D_ + d) * 2]) = p;
        }
        // Stage dmap e-slice as RTNE bf16: thread t handles its own 4 columns per d
        #pragma unroll
        for (int d = 0; d < D_; ++d) {
            const f32x4 t = *reinterpret_cast<const f32x4*>(
                dmap + ((size_t)(d * PRE_ + e)) * POST_ + o);
            u16x4 q;
            #pragma unroll
            for (int j = 0; j < 4; ++j) {
                const unsigned int u = __float_as_uint(t[j]);
                q[j] = (unsigned short)((u + 0x7FFFu + ((u >> 16) & 1u)) >> 16);
            }
            *reinterpret_cast<u16x4*>(&dm16[d * POST_ + o]) = q;  // b64, 2-way = free
        }
        __syncthreads();

        const f32x4 ap4 = *reinterpret_cast<const f32x4*>(A_p  + (size_t)e * POST_ + o);
        const f32x4 ad4 = *reinterpret_cast<const f32x4*>(A_d  + (size_t)e * POST_ + o);
        const f32x4 wm4 = *reinterpret_cast<const f32x4*>(wmax + (size_t)e * POST_ + o);

        size_t wi = (size_t)e * POST_ + o;
        #pragma unroll 1
        for (int b = 0; b < B_; ++b, wi += (size_t)PRE_ * POST_) {
            const f32x4 w4 = *reinterpret_cast<const f32x4*>(W + wi);  // cached (R13)
            const size_t go = (size_t)b * POST_ + o;
            const f32x4 xp4 = *reinterpret_cast<const f32x4*>(Xpost + go);
            const f32x4 up4 = *reinterpret_cast<const f32x4*>(u_pot + go);
            const f32x4 ud4 = *reinterpret_cast<const f32x4*>(u_dep + go);

            f32x4 sp = {0.f, 0.f, 0.f, 0.f};
            f32x4 sd = {0.f, 0.f, 0.f, 0.f};
            #pragma unroll
            for (int d = 0; d < D_; ++d) {
                const f32x2 xbd = *reinterpret_cast<const f32x2*>(
                                      &xbd_lds[(b * D_ + d) * 2]);   // uniform b64
                const u16x4 q = *reinterpret_cast<const u16x4*>(
                                      &dm16[d * POST_ + o]);         // per-thread b64
                #pragma unroll
                for (int j = 0; j < 4; ++j) {
                    const float dm = __uint_as_float((unsigned int)q[j] << 16);
                    sp[j] = fmaf(xbd.x, dm, sp[j]);
                    sd[j] = fmaf(xbd.y, dm, sd[j]);
                }
            }

            f32x4 nv;
            #pragma unroll
            for (int j = 0; j < 4; ++j) {
                const float gp = xp4[j] * fmaxf(up4[j], 0.f);  // Xpost*relu(u_pot)
                const float gd = fmaxf(ud4[j], 0.f);           // relu(u_dep)
                float wn = w4[j] + sp[j] * ap4[j] * gp - sd[j] * ad4[j] * gd;
                nv[j] = fminf(wm4[j], fmaxf(wn, 0.f));
            }
            // PLAIN stores (the A/B variable vs R13's NT stores)
            *reinterpret_cast<f32x4*>(out   + wi) = w4;
            *reinterpret_cast<f32x4*>(W_new + wi) = nv;
        }
    } else {
        // ---- filter tail: elementwise exponential filters ----
        const int i = (bid - NMAIN) * 256 + tid;   // float4 index
        const int NX = (D_ * B_ * PRE_) / 4;       // 65536
        const int NU = (B_ * POST_) / 4;           // 8192

        if (i < NX) {
            f32x4 a = *reinterpret_cast<const f32x4*>(xbar_pre + (size_t)i * 4);
            f32x4 b = *reinterpret_cast<const f32x4*>(Xd       + (size_t)i * 4);
            f32x4 r = ALPHA_X * a + (1.0f - ALPHA_X) * b;
            *reinterpret_cast<f32x4*>(xbar_new + (size_t)i * 4) = r;
        } else if (i < NX + NU) {
            const int j = i - NX;
            f32x4 a = *reinterpret_cast<const f32x4*>(u_pot + (size_t)j * 4);
            f32x4 b = *reinterpret_cast<const f32x4*>(Vpost + (size_t)j * 4);
            f32x4 r = ALPHA_P * a + (1.0f - ALPHA_P) * b;
            *reinterpret_cast<f32x4*>(u_pot_new + (size_t)j * 4) = r;
        } else {
            const int j = i - NX - NU;
            f32x4 a = *reinterpret_cast<const f32x4*>(u_dep + (size_t)j * 4);
            f32x4 b = *reinterpret_cast<const f32x4*>(Vpost + (size_t)j * 4);
            f32x4 r = ALPHA_D * a + (1.0f - ALPHA_D) * b;
            *reinterpret_cast<f32x4*>(u_dep_new + (size_t)j * 4) = r;
        }
    }
}

extern "C" void kernel_launch(void* const* d_in, const int* in_sizes, int n_in,
                              void* d_out, int out_size, void* d_ws, size_t ws_size,
                              hipStream_t stream) {
    const float* Xd       = (const float*)d_in[0];
    const float* Xpost    = (const float*)d_in[1];
    const float* Vpost    = (const float*)d_in[2];
    const float* W        = (const float*)d_in[3];
    const float* xbar_pre = (const float*)d_in[4];
    const float* u_pot    = (const float*)d_in[5];
    const float* u_dep    = (const float*)d_in[6];
    const float* dmap     = (const float*)d_in[7];
    const float* A_p      = (const float*)d_in[8];
    const float* A_d      = (const float*)d_in[9];
    const float* wmax     = (const float*)d_in[10];

    float* out        = (float*)d_out;
    float* W_new      = out + (size_t)B_ * PRE_ * POST_;
    float* xbar_new   = W_new + (size_t)B_ * PRE_ * POST_;
    float* u_pot_new  = xbar_new + (size_t)D_ * B_ * PRE_;
    float* u_dep_new  = u_pot_new + (size_t)B_ * POST_;

    clopath_fused<<<NMAIN + NFILT, 256, 0, stream>>>(
        W, dmap, A_p, A_d, wmax, xbar_pre, Xd, Xpost, Vpost, u_pot, u_dep,
        out, W_new, xbar_new, u_pot_new, u_dep_new);
}

// Round 15
// 80.064 us; speedup vs baseline: 1.4191x; 1.4191x over previous
//
#include <hip/hip_runtime.h>

#define D_ 8
#define B_ 32
#define PRE_ 1024
#define POST_ 1024

// exp(-1/10), exp(-1/20), exp(-1/15)
#define ALPHA_P 0.90483741803595952f
#define ALPHA_D 0.95122942450071400f
#define ALPHA_X 0.93550698503161731f

#define NMAIN PRE_                                            // 1024 main blocks
#define NFILT (((D_*B_*PRE_)/4 + 2*((B_*POST_)/4)) / 256)     // 320 filter blocks

typedef float f32x4 __attribute__((ext_vector_type(4)));
typedef float f32x2 __attribute__((ext_vector_type(2)));
typedef unsigned short u16x4 __attribute__((ext_vector_type(4)));

// FINAL = R13 (82.4 us), reverted byte-exact after R14's A/B.
// Memory-path map established by A/B rounds on this op:
//   - W load: PLAIN CACHED. NT load bypasses L2, shallow request queue,
//     invisible to FETCH_SIZE; cost +23 us (R10 105.0 -> R13 82.4).
//   - out/W_new stores: NON-TEMPORAL. Plain stores write-allocate 268 MB
//     through L2, evicting the read working set; cost +31 us (R14 113.6).
//   - bf16 dmap e-slice in LDS (16 KB): zero cross-thread sharing -> lossy
//     bf16 legal (absmax 0.0078 vs threshold 0.083). One HBM fetch, 32x reuse.
//   - One block per e; 16 B/lane everywhere (R7: 8 B/lane costs ~10%).
//   - Occupancy 4 vs 8 blocks/CU: neutral (R6 vs R10). ILP pipeline: neutral (R8).
//   - __launch_bounds__(256,2) only. R9: (256,6)->40 VGPR serializes loads;
//     R4: (256,8)->32 VGPR scratch-spills. Never cap below natural live state.
// Position: ~466 MB real traffic / 82.4 us = 5.7 TB/s = ~85% of the 6.5-7 TB/s
// fill/copy ceiling on this chip.
__global__ __launch_bounds__(256, 2) void clopath_fused(
    const float* __restrict__ W,
    const float* __restrict__ dmap,
    const float* __restrict__ A_p,
    const float* __restrict__ A_d,
    const float* __restrict__ wmax,
    const float* __restrict__ xbar_pre,
    const float* __restrict__ Xd,
    const float* __restrict__ Xpost,
    const float* __restrict__ Vpost,
    const float* __restrict__ u_pot,
    const float* __restrict__ u_dep,
    float* __restrict__ out,       // output 0: copy of W
    float* __restrict__ W_new,     // output 1
    float* __restrict__ xbar_new,  // output 2
    float* __restrict__ u_pot_new, // output 3
    float* __restrict__ u_dep_new) // output 4
{
    const int bid = blockIdx.x;
    const int tid = threadIdx.x;

    if (bid < NMAIN) {
        const int e = bid;                 // one block per e
        const int o = tid << 2;            // this thread's float4 of POST

        __shared__ unsigned short dm16[D_ * POST_];  // 16 KB: bf16 dmap e-slice
        __shared__ float xbd_lds[B_ * D_ * 2];       // 2 KB: (xb, xd) per (b,d)

        // Stage (xb, xd) pairs: t -> (b = t>>3, d = t&7)
        {
            const int d = tid & 7;
            const int b = tid >> 3;
            const size_t idx = ((size_t)(d * B_ + b)) * PRE_ + e;
            f32x2 p;
            p.x = xbar_pre[idx];
            p.y = Xd[idx];
            *reinterpret_cast<f32x2*>(&xbd_lds[(b * D_ + d) * 2]) = p;
        }
        // Stage dmap e-slice as RTNE bf16: thread t handles its own 4 columns per d
        #pragma unroll
        for (int d = 0; d < D_; ++d) {
            const f32x4 t = *reinterpret_cast<const f32x4*>(
                dmap + ((size_t)(d * PRE_ + e)) * POST_ + o);
            u16x4 q;
            #pragma unroll
            for (int j = 0; j < 4; ++j) {
                const unsigned int u = __float_as_uint(t[j]);
                q[j] = (unsigned short)((u + 0x7FFFu + ((u >> 16) & 1u)) >> 16);
            }
            *reinterpret_cast<u16x4*>(&dm16[d * POST_ + o]) = q;  // b64, 2-way = free
        }
        __syncthreads();

        const f32x4 ap4 = *reinterpret_cast<const f32x4*>(A_p  + (size_t)e * POST_ + o);
        const f32x4 ad4 = *reinterpret_cast<const f32x4*>(A_d  + (size_t)e * POST_ + o);
        const f32x4 wm4 = *reinterpret_cast<const f32x4*>(wmax + (size_t)e * POST_ + o);

        size_t wi = (size_t)e * POST_ + o;
        #pragma unroll 1
        for (int b = 0; b < B_; ++b, wi += (size_t)PRE_ * POST_) {
            const f32x4 w4 = *reinterpret_cast<const f32x4*>(W + wi);  // cached
            const size_t go = (size_t)b * POST_ + o;
            const f32x4 xp4 = *reinterpret_cast<const f32x4*>(Xpost + go);
            const f32x4 up4 = *reinterpret_cast<const f32x4*>(u_pot + go);
            const f32x4 ud4 = *reinterpret_cast<const f32x4*>(u_dep + go);

            f32x4 sp = {0.f, 0.f, 0.f, 0.f};
            f32x4 sd = {0.f, 0.f, 0.f, 0.f};
            #pragma unroll
            for (int d = 0; d < D_; ++d) {
                const f32x2 xbd = *reinterpret_cast<const f32x2*>(
                                      &xbd_lds[(b * D_ + d) * 2]);   // uniform b64
                const u16x4 q = *reinterpret_cast<const u16x4*>(
                                      &dm16[d * POST_ + o]);         // per-thread b64
                #pragma unroll
                for (int j = 0; j < 4; ++j) {
                    const float dm = __uint_as_float((unsigned int)q[j] << 16);
                    sp[j] = fmaf(xbd.x, dm, sp[j]);
                    sd[j] = fmaf(xbd.y, dm, sd[j]);
                }
            }

            f32x4 nv;
            #pragma unroll
            for (int j = 0; j < 4; ++j) {
                const float gp = xp4[j] * fmaxf(up4[j], 0.f);  // Xpost*relu(u_pot)
                const float gd = fmaxf(ud4[j], 0.f);           // relu(u_dep)
                float wn = w4[j] + sp[j] * ap4[j] * gp - sd[j] * ad4[j] * gd;
                nv[j] = fminf(wm4[j], fmaxf(wn, 0.f));
            }
            __builtin_nontemporal_store(w4, reinterpret_cast<f32x4*>(out   + wi));
            __builtin_nontemporal_store(nv, reinterpret_cast<f32x4*>(W_new + wi));
        }
    } else {
        // ---- filter tail: elementwise exponential filters ----
        const int i = (bid - NMAIN) * 256 + tid;   // float4 index
        const int NX = (D_ * B_ * PRE_) / 4;       // 65536
        const int NU = (B_ * POST_) / 4;           // 8192

        if (i < NX) {
            f32x4 a = *reinterpret_cast<const f32x4*>(xbar_pre + (size_t)i * 4);
            f32x4 b = *reinterpret_cast<const f32x4*>(Xd       + (size_t)i * 4);
            f32x4 r = ALPHA_X * a + (1.0f - ALPHA_X) * b;
            __builtin_nontemporal_store(r, reinterpret_cast<f32x4*>(xbar_new + (size_t)i * 4));
        } else if (i < NX + NU) {
            const int j = i - NX;
            f32x4 a = *reinterpret_cast<const f32x4*>(u_pot + (size_t)j * 4);
            f32x4 b = *reinterpret_cast<const f32x4*>(Vpost + (size_t)j * 4);
            f32x4 r = ALPHA_P * a + (1.0f - ALPHA_P) * b;
            __builtin_nontemporal_store(r, reinterpret_cast<f32x4*>(u_pot_new + (size_t)j * 4));
        } else {
            const int j = i - NX - NU;
            f32x4 a = *reinterpret_cast<const f32x4*>(u_dep + (size_t)j * 4);
            f32x4 b = *reinterpret_cast<const f32x4*>(Vpost + (size_t)j * 4);
            f32x4 r = ALPHA_D * a + (1.0f - ALPHA_D) * b;
            __builtin_nontemporal_store(r, reinterpret_cast<f32x4*>(u_dep_new + (size_t)j * 4));
        }
    }
}

extern "C" void kernel_launch(void* const* d_in, const int* in_sizes, int n_in,
                              void* d_out, int out_size, void* d_ws, size_t ws_size,
                              hipStream_t stream) {
    const float* Xd       = (const float*)d_in[0];
    const float* Xpost    = (const float*)d_in[1];
    const float* Vpost    = (const float*)d_in[2];
    const float* W        = (const float*)d_in[3];
    const float* xbar_pre = (const float*)d_in[4];
    const float* u_pot    = (const float*)d_in[5];
    const float* u_dep    = (const float*)d_in[6];
    const float* dmap     = (const float*)d_in[7];
    const float* A_p      = (const float*)d_in[8];
    const float* A_d      = (const float*)d_in[9];
    const float* wmax     = (const float*)d_in[10];

    float* out        = (float*)d_out;
    float* W_new      = out + (size_t)B_ * PRE_ * POST_;
    float* xbar_new   = W_new + (size_t)B_ * PRE_ * POST_;
    float* u_pot_new  = xbar_new + (size_t)D_ * B_ * PRE_;
    float* u_dep_new  = u_pot_new + (size_t)B_ * POST_;

    clopath_fused<<<NMAIN + NFILT, 256, 0, stream>>>(
        W, dmap, A_p, A_d, wmax, xbar_pre, Xd, Xpost, Vpost, u_pot, u_dep,
        out, W_new, xbar_new, u_pot_new, u_dep_new);
}